// Round 8
// baseline (203.638 us; speedup 1.0000x reference)
//
#include <hip/hip_runtime.h>
#include <hip/hip_bf16.h>

// Attention layer: B=2, S=2048, H=2048, NH=16, NKV=4, HD=128, N_REP=4
// cvt X->bf16; merged weight transpose; fused QKV GEMM with RoPE epilogue and
// V-transpose epilogue; strip-paired causal flash attention (KVBLK=32, 3-buf
// counted-vmcnt pipeline, uniform 66 tiles/block); O-proj GEMM (f32 out).

typedef __bf16 bf16;
typedef __bf16 bf16x8 __attribute__((ext_vector_type(8)));
typedef __bf16 bf16x4 __attribute__((ext_vector_type(4)));
typedef float  f32x4  __attribute__((ext_vector_type(4)));

#define MFMA_BF16(a, b, c) __builtin_amdgcn_mfma_f32_16x16x32_bf16((a), (b), (c), 0, 0, 0)

__device__ __forceinline__ void glds16(const bf16* g, char* l) {
  __builtin_amdgcn_global_load_lds((__attribute__((address_space(1))) const void*)g,
                                   (__attribute__((address_space(3))) void*)l, 16, 0, 0);
}

// ------------------------------------------------------------------
__global__ __launch_bounds__(256) void k_cvt_bf16(const float* __restrict__ in,
                                                  bf16* __restrict__ out, int n4) {
  int i = blockIdx.x * 256 + threadIdx.x;
  if (i < n4) {
    float4 v = ((const float4*)in)[i];
    bf16x4 o;
    o[0] = (bf16)v.x; o[1] = (bf16)v.y; o[2] = (bf16)v.z; o[3] = (bf16)v.w;
    ((bf16x4*)out)[i] = o;
  }
}

// ------------------------------------------------------------------
// Merged weight transpose: W [Kd=2048][N] f32 -> Wt [N][2048] bf16.
__global__ __launch_bounds__(256) void k_transpose_w4(const float* __restrict__ Wq,
                                                      const float* __restrict__ Wk,
                                                      const float* __restrict__ Wv,
                                                      const float* __restrict__ Wo,
                                                      bf16* __restrict__ Wtq,
                                                      bf16* __restrict__ Wtk,
                                                      bf16* __restrict__ Wtv,
                                                      bf16* __restrict__ Wto) {
  int z = blockIdx.z;
  const float* W; bf16* Wt; int N;
  if (z == 0)      { W = Wq; Wt = Wtq; N = 2048; }
  else if (z == 1) { W = Wo; Wt = Wto; N = 2048; }
  else if (z == 2) { W = Wk; Wt = Wtk; N = 512; }
  else             { W = Wv; Wt = Wtv; N = 512; }
  int nb = blockIdx.y * 32;
  if (nb >= N) return;
  __shared__ float tile[32][33];
  int tx = threadIdx.x, ty = threadIdx.y;
  int kb = blockIdx.x * 32;
#pragma unroll
  for (int i = 0; i < 4; ++i)
    tile[ty + i * 8][tx] = W[(size_t)(kb + ty + i * 8) * N + nb + tx];
  __syncthreads();
#pragma unroll
  for (int i = 0; i < 4; ++i)
    Wt[(size_t)(nb + ty + i * 8) * 2048 + kb + tx] = (bf16)tile[tx][ty + i * 8];
}

// ------------------------------------------------------------------
// GEMM 128x128 tile, BK=64, glds staging, dbuf LDS, 1 barrier/K-step.
// rope_scl != 0: fused RoPE epilogue. vtr != nullptr: V-transpose epilogue.
template <typename OUT>
__device__ void gemm_block(const bf16* __restrict__ A, const bf16* __restrict__ Bt,
                           OUT* __restrict__ C, int K, int ldc,
                           int rbase, int cbase, char* sm,
                           float rope_scl, const float* __restrict__ cosb,
                           const float* __restrict__ sinb,
                           bf16* __restrict__ vtr, int vkv) {
  const int tid = threadIdx.x;
  const int lane = tid & 63, wid = tid >> 6;
  const int l15 = lane & 15, lg = lane >> 4;
  char* Asm = sm;
  char* Bsm = sm + 32768;

  f32x4 acc[2][8];
#pragma unroll
  for (int i = 0; i < 2; ++i)
#pragma unroll
    for (int j = 0; j < 8; ++j)
#pragma unroll
      for (int r = 0; r < 4; ++r) acc[i][j][r] = 0.0f;

  const int ob = wid * 4096 + lane * 16;
  auto stage = [&](int buf, int kb) {
#pragma unroll
    for (int c = 0; c < 4; ++c) {
      int o = ob + c * 1024;
      int r = o >> 7;
      int cc = ((o >> 4) & 7) ^ (r & 7);
      int dst = wid * 4096 + c * 1024 + buf * 16384;
      glds16(A + (size_t)(rbase + r) * K + kb + cc * 8, Asm + dst);
      glds16(Bt + (size_t)(cbase + r) * K + kb + cc * 8, Bsm + dst);
    }
  };

  stage(0, 0);
  __syncthreads();
  const int nk = K >> 6;
  for (int t = 0; t < nk; ++t) {
    if (t + 1 < nk) stage((t + 1) & 1, (t + 1) << 6);
    const char* At  = Asm + (t & 1) * 16384;
    const char* Bti = Bsm + (t & 1) * 16384;
#pragma unroll
    for (int ks = 0; ks < 2; ++ks) {
      bf16x8 a[2], b[8];
#pragma unroll
      for (int rf = 0; rf < 2; ++rf) {
        int r = wid * 32 + rf * 16 + l15;
        int slot = (ks * 4 + lg) ^ (r & 7);
        a[rf] = *(const bf16x8*)(At + r * 128 + slot * 16);
      }
#pragma unroll
      for (int nf = 0; nf < 8; ++nf) {
        int n = nf * 16 + l15;
        int slot = (ks * 4 + lg) ^ (n & 7);
        b[nf] = *(const bf16x8*)(Bti + n * 128 + slot * 16);
      }
#pragma unroll
      for (int rf = 0; rf < 2; ++rf)
#pragma unroll
        for (int nf = 0; nf < 8; ++nf)
          acc[rf][nf] = MFMA_BF16(a[rf], b[nf], acc[rf][nf]);
    }
    __syncthreads();
  }

  if (rope_scl != 0.0f) {
#pragma unroll
    for (int rf = 0; rf < 2; ++rf)
#pragma unroll
      for (int r = 0; r < 4; ++r) {
        int s = (rbase + wid * 32 + rf * 16 + lg * 4 + r) & 2047;
#pragma unroll
        for (int nf = 0; nf < 4; ++nf) {
          int d = nf * 16 + l15;
          float v0 = acc[rf][nf][r], v1 = acc[rf][nf + 4][r];
          float c0 = cosb[s * 128 + d],      c1 = cosb[s * 128 + d + 64];
          float s0 = sinb[s * 128 + d],      s1 = sinb[s * 128 + d + 64];
          acc[rf][nf][r]     = (v0 * c0 - v1 * s0) * rope_scl;
          acc[rf][nf + 4][r] = (v1 * c1 + v0 * s1) * rope_scl;
        }
      }
  }

  if (vtr != nullptr) {
#pragma unroll
    for (int rf = 0; rf < 2; ++rf)
#pragma unroll
      for (int nf = 0; nf < 8; ++nf) {
        int s0 = wid * 32 + rf * 16 + lg * 4;
        int d = nf * 16 + l15;
        bf16x4 pk;
#pragma unroll
        for (int r = 0; r < 4; ++r) pk[r] = (bf16)acc[rf][nf][r];
        *(bf16x4*)(sm + d * 256 + ((s0 * 2) ^ ((d & 15) << 4))) = pk;
      }
    __syncthreads();
    const int b4 = (rbase >> 11) * 4;
    const int scol = rbase & 2047;
    const int so = tid & 15;
#pragma unroll
    for (int i = 0; i < 8; ++i) {
      int d = (tid >> 4) + i * 16;
      bf16x8 v = *(const bf16x8*)(sm + d * 256 + ((so * 16) ^ ((d & 15) << 4)));
      *(bf16x8*)(vtr + (size_t)((b4 + vkv) * 128 + d) * 2048 + scol + so * 8) = v;
    }
    return;
  }

#pragma unroll
  for (int rf = 0; rf < 2; ++rf)
#pragma unroll
    for (int nf = 0; nf < 8; ++nf)
#pragma unroll
      for (int r = 0; r < 4; ++r) {
        int row = rbase + wid * 32 + rf * 16 + lg * 4 + r;
        int col = cbase + nf * 16 + l15;
        C[(size_t)row * ldc + col] = (OUT)acc[rf][nf][r];
      }
}

__global__ __launch_bounds__(256, 2) void k_gemm_qkv(const bf16* __restrict__ X,
                                                     const bf16* __restrict__ Wtq,
                                                     const bf16* __restrict__ Wtk,
                                                     const bf16* __restrict__ Wtv,
                                                     bf16* __restrict__ Q,
                                                     bf16* __restrict__ Ko,
                                                     bf16* __restrict__ Vt,
                                                     const float* __restrict__ cosb,
                                                     const float* __restrict__ sinb,
                                                     float sclq) {
  __shared__ alignas(16) char sm[65536];
  int nb = blockIdx.y;
  int rbase = blockIdx.x * 128;
  if (nb < 16) {
    gemm_block<bf16>(X, Wtq, Q, 2048, 2048, rbase, nb * 128, sm, sclq, cosb, sinb,
                     nullptr, 0);
  } else if (nb < 20) {
    gemm_block<bf16>(X, Wtk, Ko, 2048, 512, rbase, (nb - 16) * 128, sm, 1.0f, cosb, sinb,
                     nullptr, 0);
  } else {
    gemm_block<bf16>(X, Wtv, (bf16*)nullptr, 2048, 512, rbase, (nb - 20) * 128, sm,
                     0.0f, nullptr, nullptr, Vt, nb - 20);
  }
}

__global__ __launch_bounds__(256, 2) void k_gemm_o(const bf16* __restrict__ AO,
                                                   const bf16* __restrict__ Wto,
                                                   float* __restrict__ Out) {
  __shared__ alignas(16) char sm[65536];
  gemm_block<float>(AO, Wto, Out, 2048, 2048, blockIdx.x * 128, blockIdx.y * 128, sm,
                    0.0f, nullptr, nullptr, nullptr, 0);
}

// ------------------------------------------------------------------
// Strip-paired causal flash attention. Block processes strip sA=31-p (long)
// then sB=p (short) sequentially: uniform 66 KVBLK=32 tiles/block, same (b,kv)
// K/V pointers for both. 3-buffer K/V pipeline with counted s_waitcnt vmcnt(4)
// + raw s_barrier (never drain to 0 in the loop). Grid 512 (wg&7 = XCD (b,kv)
// group), 2 blocks/CU, LDS 53KB.
__global__ __launch_bounds__(256, 2) void k_fattn(const bf16* __restrict__ Qg,
                                                  const bf16* __restrict__ Kg,
                                                  const bf16* __restrict__ Vtg,
                                                  bf16* __restrict__ AO) {
  __shared__ alignas(16) char sm[54272];
  // bufs: 3 x [K 8KB | V 8KB] at buf*16384 ; P: 49152 + wid*1280
  const int lane = threadIdx.x & 63, wid = threadIdx.x >> 6;
  const int l15 = lane & 15, lg = lane >> 4;
  const int wg = blockIdx.x;
  const int grp = wg & 7;
  const int b = grp >> 2, kv = grp & 3;
  const int inner = wg >> 3;          // 0..63
  const int h = kv * 4 + (inner & 3);
  const int pair = inner >> 2;        // 0..15
  const int sA = 31 - pair, sB = pair;
  const int nA = 2 * (sA + 1);
  const int NT = nA + 2 * (sB + 1);   // = 66
  const int q0A = sA * 64 + wid * 16, q0B = sB * 64 + wid * 16;
  char* Pw = sm + 49152 + wid * 1280;

  // Q fragments for both strips (kept in regs; no mid-pipeline global loads)
  bf16x8 qfA[4], qfB[4];
#pragma unroll
  for (int kf = 0; kf < 4; ++kf) {
    qfA[kf] = *(const bf16x8*)(Qg + (size_t)(b * 2048 + q0A + l15) * 2048 + h * 128 + kf * 32 + lg * 8);
    qfB[kf] = *(const bf16x8*)(Qg + (size_t)(b * 2048 + q0B + l15) * 2048 + h * 128 + kf * 32 + lg * 8);
  }

  f32x4 o[8];
#pragma unroll
  for (int j = 0; j < 8; ++j)
#pragma unroll
    for (int r = 0; r < 4; ++r) o[j][r] = 0.0f;
  float mrun = -3e38f, lrun = 0.0f;

  // per-thread staging bases (inverse-swizzled global sources)
  const bf16* ksrc0[2];
  const bf16* vsrc0[2];
  int kdst[2], vdst[2];
#pragma unroll
  for (int j = 0; j < 2; ++j) {
    int c = wid * 128 + j * 64 + lane;
    int kr = c >> 4, kslot = c & 15;
    int kcc = kslot ^ (kr & 15);
    ksrc0[j] = Kg + (size_t)(b * 2048 + kr) * 512 + kv * 128 + kcc * 8;
    kdst[j] = wid * 2048 + j * 1024;
    int vr = c >> 2, vslot = c & 3;
    int vcc = vslot ^ ((vr >> 1) & 3);
    vsrc0[j] = Vtg + (size_t)((b * 4 + kv) * 128 + vr) * 2048 + vcc * 8;
    vdst[j] = 8192 + wid * 2048 + j * 1024;
  }

  auto stage = [&](int i) {   // flat tile index
    if (i >= NT) return;
    int kb = ((i < nA) ? i : i - nA) << 5;
    char* bb = sm + (i % 3) * 16384;
#pragma unroll
    for (int j = 0; j < 2; ++j) {
      glds16(ksrc0[j] + (size_t)kb * 512, bb + kdst[j]);
      glds16(vsrc0[j] + kb, bb + vdst[j]);
    }
  };

  auto tile = [&](int t, int kb, const bf16x8 (&qf)[4], int q0) {
    stage(t + 2);
    const char* Kt = sm + (t % 3) * 16384;
    const char* Vt = Kt + 8192;

    // S^T = K Q^T : rows k = nf*16+lg*4+r, col q = l15
    f32x4 sa[2];
#pragma unroll
    for (int j = 0; j < 2; ++j)
#pragma unroll
      for (int r = 0; r < 4; ++r) sa[j][r] = 0.0f;
    __builtin_amdgcn_s_setprio(1);
#pragma unroll
    for (int kf = 0; kf < 4; ++kf) {
#pragma unroll
      for (int nf = 0; nf < 2; ++nf) {
        int slot = (kf * 4 + lg) ^ l15;
        bf16x8 bk = *(const bf16x8*)(Kt + (nf * 16 + l15) * 256 + slot * 16);
        sa[nf] = MFMA_BF16(bk, qf[kf], sa[nf]);
      }
    }
    __builtin_amdgcn_s_setprio(0);

    if (kb + 31 > q0) {
      const int qi = q0 + l15;
#pragma unroll
      for (int nf = 0; nf < 2; ++nf)
#pragma unroll
        for (int r = 0; r < 4; ++r)
          if (kb + nf * 16 + lg * 4 + r > qi) sa[nf][r] = -3e38f;
    }

    float mx = sa[0][0];
#pragma unroll
    for (int nf = 0; nf < 2; ++nf)
#pragma unroll
      for (int r = 0; r < 4; ++r) mx = fmaxf(mx, sa[nf][r]);
    mx = fmaxf(mx, __shfl_xor(mx, 16));
    mx = fmaxf(mx, __shfl_xor(mx, 32));
    if (!__all(mx - mrun <= 8.0f)) {       // defer-max (THR=8)
      float mnew = fmaxf(mrun, mx);
      float fac = __builtin_amdgcn_exp2f(mrun - mnew);
      lrun *= fac;
      f32x4 fv;
#pragma unroll
      for (int r = 0; r < 4; ++r) fv[r] = __shfl(fac, lg * 4 + r);
#pragma unroll
      for (int j = 0; j < 8; ++j) o[j] *= fv;
      mrun = mnew;
    }
    float rs = 0.0f;
#pragma unroll
    for (int nf = 0; nf < 2; ++nf) {
      bf16x4 pk;
#pragma unroll
      for (int r = 0; r < 4; ++r) {
        float p = __builtin_amdgcn_exp2f(sa[nf][r] - mrun);
        rs += p;
        pk[r] = (bf16)p;
      }
      *(bf16x4*)(Pw + l15 * 80 + nf * 32 + lg * 8) = pk;
    }
    rs += __shfl_xor(rs, 16);
    rs += __shfl_xor(rs, 32);
    lrun += rs;

    bf16x8 pa = *(const bf16x8*)(Pw + l15 * 80 + lg * 16);
    __builtin_amdgcn_s_setprio(1);
#pragma unroll
    for (int nf2 = 0; nf2 < 8; ++nf2) {
      int d = nf2 * 16 + l15;
      int slot = lg ^ ((d >> 1) & 3);
      bf16x8 vb = *(const bf16x8*)(Vt + d * 64 + slot * 16);
      o[nf2] = MFMA_BF16(pa, vb, o[nf2]);
    }
    __builtin_amdgcn_s_setprio(0);

    // counted waits: keep stage(t+2) in flight across the barrier
    if (t + 2 < NT) {
      asm volatile("s_waitcnt vmcnt(4)" ::: "memory");
      __builtin_amdgcn_s_barrier();
    } else if (t + 1 < NT) {
      asm volatile("s_waitcnt vmcnt(0)" ::: "memory");
      __builtin_amdgcn_s_barrier();
    }
  };

  auto epi = [&](int q0) {
    f32x4 linv;
#pragma unroll
    for (int r = 0; r < 4; ++r) linv[r] = 1.0f / __shfl(lrun, lg * 4 + r);
#pragma unroll
    for (int j = 0; j < 8; ++j)
#pragma unroll
      for (int r = 0; r < 4; ++r) {
        size_t row = (size_t)(b * 2048 + q0 + lg * 4 + r);
        AO[row * 2048 + h * 128 + j * 16 + l15] = (bf16)(o[j][r] * linv[r]);
      }
  };

  // prologue: 2 tiles in flight; wait tile0 only
  stage(0);
  stage(1);
  asm volatile("s_waitcnt vmcnt(4)" ::: "memory");
  __builtin_amdgcn_s_barrier();

  for (int t = 0; t < nA; ++t) tile(t, t << 5, qfA, q0A);
  epi(q0A);
#pragma unroll
  for (int j = 0; j < 8; ++j)
#pragma unroll
    for (int r = 0; r < 4; ++r) o[j][r] = 0.0f;
  mrun = -3e38f; lrun = 0.0f;
  for (int t = nA; t < NT; ++t) tile(t, (t - nA) << 5, qfB, q0B);
  epi(q0B);
}

// ------------------------------------------------------------------
extern "C" void kernel_launch(void* const* d_in, const int* in_sizes, int n_in,
                              void* d_out, int out_size, void* d_ws, size_t ws_size,
                              hipStream_t stream) {
  const float* hs   = (const float*)d_in[0];
  const float* cosb = (const float*)d_in[1];
  const float* sinb = (const float*)d_in[2];
  const float* Wq   = (const float*)d_in[3];
  const float* Wk   = (const float*)d_in[4];
  const float* Wv   = (const float*)d_in[5];
  const float* Wo   = (const float*)d_in[6];
  float* Out = (float*)d_out;

  char* ws = (char*)d_ws;
  size_t off = 0;
  auto alloc = [&](size_t bytes) { char* p = ws + off; off += bytes; return p; };
  bf16* Xbf = (bf16*)alloc((size_t)4096 * 2048 * 2);
  bf16* Wtq = (bf16*)alloc((size_t)2048 * 2048 * 2);
  bf16* Wtk = (bf16*)alloc((size_t)512 * 2048 * 2);
  bf16* Wtv = (bf16*)alloc((size_t)512 * 2048 * 2);
  bf16* Wto = (bf16*)alloc((size_t)2048 * 2048 * 2);
  bf16* Qb  = (bf16*)alloc((size_t)4096 * 2048 * 2);
  bf16* Kb  = (bf16*)alloc((size_t)4096 * 512 * 2);
  bf16* Vtb = (bf16*)alloc((size_t)4096 * 512 * 2);
  bf16* AO  = (bf16*)alloc((size_t)4096 * 2048 * 2);

  const float SCLQ = 0.08838834764831845f * 1.4426950408889634f;

  dim3 tb(32, 8);
  k_cvt_bf16<<<8192, 256, 0, stream>>>(hs, Xbf, 2097152);
  k_transpose_w4<<<dim3(64, 64, 4), tb, 0, stream>>>(Wq, Wk, Wv, Wo, Wtq, Wtk, Wtv, Wto);
  k_gemm_qkv<<<dim3(32, 24), 256, 0, stream>>>(Xbf, Wtq, Wtk, Wtv, Qb, Kb, Vtb,
                                               cosb, sinb, SCLQ);
  k_fattn<<<512, 256, 0, stream>>>(Qb, Kb, Vtb, AO);
  k_gemm_o<<<dim3(32, 16), 256, 0, stream>>>(AO, Wto, Out);
}